// Round 17
// baseline (6170.304 us; speedup 1.0000x reference)
//
#include <hip/hip_runtime.h>

// ---------------------------------------------------------------------------
// SDKT model: embeddings -> biLSTM encoder -> enc LSTM -> dec LSTM -> MLP head
// B=256, T=256, H=512, G=2048, enc/dec input = 288, enc2 input = 1024.
// == r16 (measured best 5.82 ms) + r17 change: high-volume output stores
// (gemm epilogue xg/hidden, embed enc_x/dec_x) use AGENT-SCOPE WRITE-THROUGH
// stores (stA_u16, the proven h-exchange primitive) so kernel outputs stream
// to the coherence point during the kernel instead of being flushed from
// dirty L2 at the dispatch boundary (~120 us/boundary measured in r16). ==
// GEMMs: m97-style 128x128 tile, BK=32, global_load_lds(16B), 2-barrier loop,
// LDS XOR-swizzle, PRE-PERMUTED W_ih rows/biases (linear gate-interleaved xg
// write). Small 256-thr blocks. xg layout [row][h][g]: LSTM reads one u64.
// Recurrences: persistent chunk kernels (w_hh in VGPRs, agent-atomic h
// exchange, 8-block group barrier, c in regs per chunk). Phases 2/3 at
// CHe=2*CH over the contiguous X1|X2 span. Activations TIME-MAJOR [T][B][*].
// ---------------------------------------------------------------------------

using u16 = unsigned short;
using u32 = unsigned int;
using u64 = unsigned long long;
typedef float f32x4 __attribute__((ext_vector_type(4)));
typedef __bf16 bf16x8 __attribute__((ext_vector_type(8)));

__device__ __forceinline__ u16 f2bf(float f) {
  u32 u = __float_as_uint(f);
  u = (u + 0x7FFFu + ((u >> 16) & 1u)) >> 16;  // RNE
  return (u16)u;
}
__device__ __forceinline__ float bf2f(u16 h) { return __uint_as_float(((u32)h) << 16); }
__device__ __forceinline__ float sigm(float x) { return 1.f / (1.f + __expf(-x)); }
__device__ __forceinline__ float tnh(float x) {
  float a = fabsf(x), e = __expf(-2.f * a);
  float t = (1.f - e) / (1.f + e);
  return x < 0.f ? -t : t;
}
__device__ __forceinline__ u64 ldA_u64(const u16* p) {
  return __hip_atomic_load((const u64*)p, __ATOMIC_RELAXED, __HIP_MEMORY_SCOPE_AGENT);
}
__device__ __forceinline__ void stA_u16(u16* p, u16 v) {
  __hip_atomic_store(p, v, __ATOMIC_RELAXED, __HIP_MEMORY_SCOPE_AGENT);
}
__device__ __forceinline__ void gload_lds16(const u16* g, u16* l) {
  __builtin_amdgcn_global_load_lds(
      (const __attribute__((address_space(1))) unsigned int*)g,
      (__attribute__((address_space(3))) unsigned int*)l, 16, 0, 0);
}

static const long SLOT_BI = 256L * 1024;
static const long SLOT_DO = 256L * 512;
static const long SLOT_XG = 256L * 2048;

// ---------------------------------------------------------------------------
// GEMM body: C = act(A@W^T + bias). Tile 128x128, BK=32, global_load_lds
// staging, 2 barriers/K-step. LDS tiles XOR-SWIZZLED (pre-swizzled global
// source, swizzled fragment read). Epilogue: AGENT write-through stores.
// ---------------------------------------------------------------------------
template <int ACT, int KSTEPS>
__device__ __forceinline__ void gemm_body(
    const u16* __restrict__ A1, long lda1, const u16* __restrict__ A2, long lda2, int ksplit,
    const u16* __restrict__ W, long ldw, const float* __restrict__ bias,
    u16* __restrict__ C, long ldc, int bx, int by, u16* sA, u16* sB) {
  const int tid = threadIdx.x;
  const int w = tid >> 6, lane = tid & 63;
  const int lr = lane & 15, lg = lane >> 4;
  const long mbase = (long)by * 128;
  const long nbase = (long)bx * 128;
  const int wm = (w >> 1) * 64, wn = (w & 1) * 64;
  // staging decomposition: lane -> linear LDS slot; inverse-swizzle source
  const int s_r = lane >> 2, s_q = lane & 3;
  const int u_ = s_r >> 1;                 // 128B pair index within chunk
  const int sp = ((s_r & 1) << 2) | s_q;   // physical slot within 128B
  const int s_log = sp ^ u_;               // logical slot (involution)
  const int q_log = s_log & 3;             // k-chunk (16B) within row
  const int ric = u_ * 2 + (s_log >> 2);   // logical row within 16-row chunk
  f32x4 acc[4][4] = {};
#pragma unroll 1
  for (int ks = 0; ks < KSTEPS; ks++) {
    const int kk = ks * 32;
    const u16* Asrc;
    long alda;
    int kofs;
    if (kk < ksplit) { Asrc = A1; alda = lda1; kofs = kk; }
    else             { Asrc = A2; alda = lda2; kofs = kk - ksplit; }
#pragma unroll
    for (int j = 0; j < 2; j++) {
      const int c = w * 2 + j;
      const long row = c * 16 + ric;
      gload_lds16(Asrc + (mbase + row) * alda + kofs + q_log * 8, sA + c * 512);
      gload_lds16(W + (nbase + row) * ldw + kk + q_log * 8, sB + c * 512);
    }
    __syncthreads();
    bf16x8 a[4], b[4];
#pragma unroll
    for (int f = 0; f < 4; f++) {
      const int ra = wm + f * 16 + lr;
      const int rb = wn + f * 16 + lr;
      const int oa = (ra >> 1) * 64 + (((((ra & 1) << 2) | lg) ^ ((ra >> 1) & 7)) << 3);
      const int ob = (rb >> 1) * 64 + (((((rb & 1) << 2) | lg) ^ ((rb >> 1) & 7)) << 3);
      a[f] = *reinterpret_cast<const bf16x8*>(sA + oa);
      b[f] = *reinterpret_cast<const bf16x8*>(sB + ob);
    }
#pragma unroll
    for (int fm = 0; fm < 4; fm++)
#pragma unroll
      for (int fn = 0; fn < 4; fn++)
        acc[fm][fn] = __builtin_amdgcn_mfma_f32_16x16x32_bf16(a[fm], b[fn], acc[fm][fn], 0, 0, 0);
    __syncthreads();
  }
#pragma unroll
  for (int fm = 0; fm < 4; fm++)
#pragma unroll
    for (int fn = 0; fn < 4; fn++)
#pragma unroll
      for (int r = 0; r < 4; r++) {
        const long row = mbase + wm + fm * 16 + lg * 4 + r;  // C/D: row=(lane>>4)*4+reg
        const long col = nbase + wn + fn * 16 + lr;          //      col=lane&15
        float v = acc[fm][fn][r] + bias[col];
        if (ACT == 1) v = tnh(v);
        stA_u16(&C[row * ldc + col], f2bf(v));  // write-through: no dirty L2
      }
}

template <int ACT, int KSTEPS>
__global__ __launch_bounds__(256) void gemm_tile_k(
    const u16* __restrict__ A1, long lda1, const u16* __restrict__ A2, long lda2, int ksplit,
    const u16* __restrict__ W, long ldw, const float* __restrict__ bias,
    u16* __restrict__ C, long ldc) {
  __shared__ u16 sA[4096];
  __shared__ u16 sB[4096];
  gemm_body<ACT, KSTEPS>(A1, lda1, A2, lda2, ksplit, W, ldw, bias, C, ldc,
                         blockIdx.x, blockIdx.y, sA, sB);
}

// two K=288 xg jobs in one dispatch (z picks bif / bib)
struct XGJob2 {
  const u16 *Aa, *Ab, *Wa, *Wb;
  const float *ba, *bb;
  u16 *Xa, *Xb;
};
__global__ __launch_bounds__(256) void gemm_xg2_k(XGJob2 j) {
  __shared__ u16 sA[4096];
  __shared__ u16 sB[4096];
  if (blockIdx.z == 0)
    gemm_body<0, 9>(j.Aa, 288, nullptr, 0, 1 << 30, j.Wa, 288, j.ba, j.Xa, 2048,
                    blockIdx.x, blockIdx.y, sA, sB);
  else
    gemm_body<0, 9>(j.Ab, 288, nullptr, 0, 1 << 30, j.Wb, 288, j.bb, j.Xb, 2048,
                    blockIdx.x, blockIdx.y, sA, sB);
}

// ---------------------------------------------------------------------------
// Persistent chunk LSTM (r12-proven, generic in CH/k). MODE 0: biLSTM
// (2 dirs, history=bi, stride 1024). MODE 1: enc (ping-pong h0/h1).
// MODE 2: dec (FULL decout buffer, init h0, c continues).
// ---------------------------------------------------------------------------
struct SeqP {
  const u16 *xgA, *xgB;
  const u16 *whA, *whB;
  float *cA, *cB;
  u16 *histA;
  u16 *h0, *h1;
  u32 *cnt;
  int k, CH;
};

template <int MODE>
__global__ __launch_bounds__(512, 2) void lstm_seq_k(SeqP p) {
  const int tid = threadIdx.x;
  const int w = tid >> 6, lane = tid & 63, lr = lane & 15, lg = lane >> 4;
  const int hct = w & 3, kh = w >> 2;
  int dir, rt, kb;
  if (MODE == 0) { dir = blockIdx.x >> 7; rt = (blockIdx.x >> 3) & 15; kb = blockIdx.x & 7; }
  else           { dir = 0;               rt = blockIdx.x >> 3;        kb = blockIdx.x & 7; }
  const u16* xg = (MODE == 0 && dir) ? p.xgB : p.xgA;
  const u16* wh = (MODE == 0 && dir) ? p.whB : p.whA;
  float* cbuf   = (MODE == 0 && dir) ? p.cB  : p.cA;
  const int rbase = rt * 16;
  const int hc0 = kb * 64 + hct * 16;
  const int kofs = kh * 256;
  u32* cnt = p.cnt + (long)((MODE == 0) ? (dir * 16 + rt) : rt) * 32;

  bf16x8 W[4][8];
#pragma unroll
  for (int g = 0; g < 4; g++)
#pragma unroll
    for (int ki = 0; ki < 8; ki++)
      W[g][ki] = *reinterpret_cast<const bf16x8*>(
          wh + (long)(g * 512 + hc0 + lr) * 512 + kofs + ki * 32 + lg * 8);

  const bool zero_init = (MODE <= 1) && (p.k == 0);
  float creg[4];
#pragma unroll
  for (int r = 0; r < 4; r++) {
    creg[r] = 0.f;
    if (kh == 0 && !zero_init)
      creg[r] = cbuf[(long)(rbase + lg * 4 + r) * 512 + hc0 + lr];
  }

  // [hct][g][lane]: lane stride 16B -> conflict-free
  __shared__ f32x4 lacc[4][4][64];  // 16 KB

  for (int ts = 0; ts < p.CH; ts++) {
    const int S = p.k * p.CH + ts;
    const u16* hp;
    u16* ho;
    long hstride;
    int slot;
    bool first;
    if (MODE == 0) {
      const int t = dir == 0 ? S : 255 - S;
      slot = dir == 0 ? ts : p.CH - 1 - ts;
      hstride = 1024;
      const int tp = dir == 0 ? t - 1 : t + 1;
      hp = p.histA + (long)tp * SLOT_BI + dir * 512;
      ho = p.histA + (long)t * SLOT_BI + dir * 512;
      first = (S == 0);
    } else if (MODE == 1) {
      slot = ts; hstride = 512;
      hp = (S & 1) ? p.h1 : p.h0;
      ho = (S & 1) ? p.h0 : p.h1;
      first = (S == 0);
    } else {
      slot = ts; hstride = 512;
      hp = (S == 0) ? p.h0 : p.histA + (long)(S - 1) * SLOT_DO;
      ho = p.histA + (long)S * SLOT_DO;
      first = false;
    }

    // hoisted xg loads: gate-interleaved -> one u64 per r
    u64 xq[4];
    if (kh == 0) {
      const long xb2 = (long)slot * SLOT_XG;
      const int colh = hc0 + lr;
#pragma unroll
      for (int r = 0; r < 4; r++)
        xq[r] = *reinterpret_cast<const u64*>(
            xg + xb2 + (long)(rbase + lg * 4 + r) * 2048 + colh * 4);
    }

    f32x4 acc[4] = {};
    if (!first) {
      union AU { u64 q[2]; bf16x8 v; } au[8];
      const u16* abase = hp + (long)(rbase + lr) * hstride + kofs;
#pragma unroll
      for (int ki = 0; ki < 8; ki++) {
        au[ki].q[0] = ldA_u64(abase + ki * 32 + lg * 8);
        au[ki].q[1] = ldA_u64(abase + ki * 32 + lg * 8 + 4);
      }
#pragma unroll
      for (int ki = 0; ki < 8; ki++) {
#pragma unroll
        for (int g = 0; g < 4; g++)
          acc[g] = __builtin_amdgcn_mfma_f32_16x16x32_bf16(au[ki].v, W[g][ki], acc[g], 0, 0, 0);
      }
    }
    if (kh == 1) {
#pragma unroll
      for (int g = 0; g < 4; g++) lacc[hct][g][lane] = acc[g];
    }
    __syncthreads();
    if (kh == 0) {
#pragma unroll
      for (int g = 0; g < 4; g++) acc[g] += lacc[hct][g][lane];
#pragma unroll
      for (int r = 0; r < 4; r++) {
        const long row = rbase + lg * 4 + r;
        const int colh = hc0 + lr;
        float gi = acc[0][r] + bf2f((u16)(xq[r]));
        float gf = acc[1][r] + bf2f((u16)(xq[r] >> 16));
        float gg = acc[2][r] + bf2f((u16)(xq[r] >> 32));
        float go = acc[3][r] + bf2f((u16)(xq[r] >> 48));
        float cn = sigm(gf) * creg[r] + sigm(gi) * tnh(gg);
        creg[r] = cn;
        stA_u16(&ho[row * hstride + colh], f2bf(sigm(go) * tnh(cn)));
      }
    }
    __syncthreads();  // vmcnt(0) drained: h stores at coherence point
    if (tid == 0) {
      __hip_atomic_fetch_add(cnt, 1u, __ATOMIC_RELAXED, __HIP_MEMORY_SCOPE_AGENT);
      if (ts != p.CH - 1) {
        const u32 tgt = 8u * (u32)(S + 1);
        while (__hip_atomic_load(cnt, __ATOMIC_RELAXED, __HIP_MEMORY_SCOPE_AGENT) < tgt)
          __builtin_amdgcn_s_sleep(1);
      }
    }
    __syncthreads();
  }
  if (kh == 0) {
#pragma unroll
    for (int r = 0; r < 4; r++)
      cbuf[(long)(rbase + lg * 4 + r) * 512 + hc0 + lr] = creg[r];
  }
}

// ---------------------------------------------------------------------------
// Init: weight converts (w_ih ROWS PERMUTED to gate-interleave: row' =
// (row&511)*4 + row>>9), bias folds (permuted), counter zero — ONE dispatch.
// ---------------------------------------------------------------------------
struct WcvP {
  const float* s[9]; u16* d[9]; long n[9]; int permK[9];
  const float *ba[4], *bb[4]; float* bd[4];
  u32* cnt;
};
__global__ __launch_bounds__(256) void initw_k(WcvP w) {
  const long g0 = (long)blockIdx.x * 256 + threadIdx.x;
  const long gs = (long)gridDim.x * 256;
  for (int seg = 0; seg < 9; seg++) {
    const int K = w.permK[seg];
    if (K) {
      for (long i = g0; i < w.n[seg]; i += gs) {
        const long row = i / K, kk = i - row * K;
        const long pr = ((row & 511) << 2) | (row >> 9);
        w.d[seg][pr * K + kk] = f2bf(w.s[seg][i]);
      }
    } else {
      for (long i = g0; i < w.n[seg]; i += gs) w.d[seg][i] = f2bf(w.s[seg][i]);
    }
  }
  for (int seg = 0; seg < 4; seg++)
    for (long i = g0; i < 2048; i += gs) {
      const long pi = ((i & 511) << 2) | (i >> 9);
      w.bd[seg][pi] = w.ba[seg][i] + w.bb[seg][i];
    }
  for (long i = g0; i < 64 * 32; i += gs) w.cnt[i] = 0;
}

// ---------------------------------------------------------------------------
// Both embedding gathers in ONE kernel -> bf16, TIME-MAJOR (row = t*256+b).
// Outputs via agent write-through (consumed by later dispatches anyway).
// ---------------------------------------------------------------------------
__global__ __launch_bounds__(256) void embed_k(
    const int* __restrict__ eq, const int* __restrict__ ea, const int* __restrict__ epos,
    const int* __restrict__ efmt, const int* __restrict__ dq, const int* __restrict__ da,
    const int* __restrict__ dpos, const int* __restrict__ dfmt, const int* __restrict__ last_a,
    const float* __restrict__ tw, const float* __restrict__ aw,
    const float* __restrict__ pw, const float* __restrict__ fw,
    u16* __restrict__ eout, u16* __restrict__ dout) {
  for (long row = blockIdx.x; row < 65536; row += gridDim.x) {
    const int t = (int)(row >> 8), b = (int)(row & 255);
    const long src = (long)b * 256 + t;  // inputs are [B][T]
    {
      const int iq = eq[src], ia = ea[src], ip = epos[src], ifm = efmt[src];
      for (int col = threadIdx.x; col < 288; col += 256) {
        float v;
        if (col < 128)      v = tw[(long)iq * 128 + col];
        else if (col < 256) v = aw[(long)ia * 128 + (col - 128)];
        else if (col < 272) v = pw[(long)ip * 16 + (col - 256)];
        else                v = fw[(long)ifm * 16 + (col - 272)];
        stA_u16(&eout[row * 288 + col], f2bf(v));
      }
    }
    {
      const int iq = dq[src], ip = dpos[src], ifm = dfmt[src];
      const int pa = (t == 0) ? last_a[b] : da[src - 1];  // teacher forcing shift
      for (int col = threadIdx.x; col < 288; col += 256) {
        float v;
        if (col < 128)      v = tw[(long)iq * 128 + col];
        else if (col < 144) v = pw[(long)ip * 16 + (col - 128)];
        else if (col < 160) v = fw[(long)ifm * 16 + (col - 144)];
        else                v = aw[(long)pa * 128 + (col - 160)];
        stA_u16(&dout[row * 288 + col], f2bf(v));
      }
    }
  }
}

// out[b*256+t] = sigmoid(hidden[t*256+b] . w2 + b2); grid-stride, 1 wave/row.
__global__ __launch_bounds__(256) void pred_out_k(
    const u16* __restrict__ hidden, const float* __restrict__ w2,
    const float* __restrict__ b2, float* __restrict__ out) {
  const int lane = threadIdx.x & 63;
  const float* wp = w2 + lane * 8;
  float wv[8];
#pragma unroll
  for (int j = 0; j < 8; j++) wv[j] = wp[j];
  const float bv = b2[0];
  for (long r = (long)blockIdx.x * 4 + (threadIdx.x >> 6); r < 65536; r += 8192) {
    const u16* hp = hidden + r * 512 + lane * 8;
    float s = 0.f;
#pragma unroll
    for (int j = 0; j < 8; j++) s += bf2f(hp[j]) * wv[j];
    for (int off = 32; off > 0; off >>= 1) s += __shfl_down(s, off);
    if (lane == 0) out[(r & 255) * 256 + (r >> 8)] = sigm(s + bv);
  }
}

// ---------------------------------------------------------------------------
extern "C" void kernel_launch(void* const* d_in, const int* in_sizes, int n_in,
                              void* d_out, int out_size, void* d_ws, size_t ws_size,
                              hipStream_t stream) {
  const int* enc_q     = (const int*)d_in[0];
  const int* enc_a     = (const int*)d_in[1];
  const int* enc_pos   = (const int*)d_in[2];
  const int* enc_fmt   = (const int*)d_in[3];
  const int* dec_q     = (const int*)d_in[4];
  const int* dec_a     = (const int*)d_in[5];
  const int* dec_pos   = (const int*)d_in[6];
  const int* dec_fmt   = (const int*)d_in[7];
  const int* enc_last  = (const int*)d_in[8];
  const float* t_emb   = (const float*)d_in[9];
  const float* a_emb   = (const float*)d_in[10];
  const float* pos_emb = (const float*)d_in[11];
  const float* fmt_emb = (const float*)d_in[12];
  const float* bif_w_ih = (const float*)d_in[13];
  const float* bif_w_hh = (const float*)d_in[14];
  const float* bif_b_ih = (const float*)d_in[15];
  const float* bif_b_hh = (const float*)d_in[16];
  const float* bib_w_ih = (const float*)d_in[17];
  const float* bib_w_hh = (const float*)d_in[18];
  const float* bib_b_ih = (const float*)d_in[19];
  const float* bib_b_hh = (const float*)d_in[20];
  const float* enc_w_ih = (const float*)d_in[21];
  const float* enc_w_hh = (const float*)d_in[22];
  const float* enc_b_ih = (const float*)d_in[23];
  const float* enc_b_hh = (const float*)d_in[24];
  const float* dec_w_ih = (const float*)d_in[25];
  const float* dec_w_hh = (const float*)d_in[26];
  const float* dec_b_ih = (const float*)d_in[27];
  const float* dec_b_hh = (const float*)d_in[28];
  const float* pred_w1 = (const float*)d_in[29];
  const float* pred_b1 = (const float*)d_in[30];
  const float* pred_w2 = (const float*)d_in[31];
  const float* pred_b2 = (const float*)d_in[32];
  (void)in_sizes; (void)n_in; (void)out_size;

  char* base = (char*)d_ws;
  size_t off = 0;
  auto alloc = [&](size_t bytes) -> char* {
    char* p = base + off;
    off = (off + bytes + 255) & ~(size_t)255;
    return p;
  };

  // --- fixed region ---
  u16* wb_bif_ih = (u16*)alloc(2048L * 288 * 2);
  u16* wb_bib_ih = (u16*)alloc(2048L * 288 * 2);
  u16* wb_enc_ih = (u16*)alloc(2048L * 1024 * 2);
  u16* wb_dec_ih = (u16*)alloc(2048L * 288 * 2);
  u16* wb_bif_hh = (u16*)alloc(2048L * 512 * 2);
  u16* wb_bib_hh = (u16*)alloc(2048L * 512 * 2);
  u16* wb_enc_hh = (u16*)alloc(2048L * 512 * 2);
  u16* wb_dec_hh = (u16*)alloc(2048L * 512 * 2);
  u16* wb_pred1  = (u16*)alloc(512L * 672 * 2);
  float* bias_bif = (float*)alloc(2048 * 4);
  float* bias_bib = (float*)alloc(2048 * 4);
  float* bias_enc = (float*)alloc(2048 * 4);
  float* bias_dec = (float*)alloc(2048 * 4);
  float* c_bif = (float*)alloc(256L * 512 * 4);
  float* c_bib = (float*)alloc(256L * 512 * 4);
  float* c_enc = (float*)alloc(256L * 512 * 4);
  u16* h_enc0 = (u16*)alloc(256L * 512 * 2);
  u16* h_enc1 = (u16*)alloc(256L * 512 * 2);
  u32* cnt = (u32*)alloc(64L * 32 * 4);

  // --- big activations (time-major) ---
  u16* bi    = (u16*)alloc(65536L * 1024 * 2);  // phase1/2; decout+hidden alias
  u16* dec_x = (u16*)alloc(65536L * 288 * 2);
  u16* enc_x = (u16*)alloc(65536L * 288 * 2);

  int CH = 128;
  while (CH > 8 && off + 2ull * CH * 256 * 2048 * 2 > ws_size) CH >>= 1;
  u16* X1 = (u16*)alloc((size_t)CH * 256 * 2048 * 2);
  u16* X2 = (u16*)alloc((size_t)CH * 256 * 2048 * 2);  // contiguous after X1
  u16* decout = bi;                 // [65536][512], bi dead after phase 2
  u16* hidden = bi + 65536L * 512;  // [65536][512]
  const int NCH = 256 / CH;
  const int CHe = (CH * 2 <= 256) ? CH * 2 : 256;  // phases 2/3 use X1|X2 span
  const int NCH2 = 256 / CHe;

  WcvP wc;
  wc.s[0] = bif_w_ih; wc.d[0] = wb_bif_ih; wc.n[0] = 2048L * 288;  wc.permK[0] = 288;
  wc.s[1] = bib_w_ih; wc.d[1] = wb_bib_ih; wc.n[1] = 2048L * 288;  wc.permK[1] = 288;
  wc.s[2] = enc_w_ih; wc.d[2] = wb_enc_ih; wc.n[2] = 2048L * 1024; wc.permK[2] = 1024;
  wc.s[3] = dec_w_ih; wc.d[3] = wb_dec_ih; wc.n[3] = 2048L * 288;  wc.permK[3] = 288;
  wc.s[4] = bif_w_hh; wc.d[4] = wb_bif_hh; wc.n[4] = 2048L * 512;  wc.permK[4] = 0;
  wc.s[5] = bib_w_hh; wc.d[5] = wb_bib_hh; wc.n[5] = 2048L * 512;  wc.permK[5] = 0;
  wc.s[6] = enc_w_hh; wc.d[6] = wb_enc_hh; wc.n[6] = 2048L * 512;  wc.permK[6] = 0;
  wc.s[7] = dec_w_hh; wc.d[7] = wb_dec_hh; wc.n[7] = 2048L * 512;  wc.permK[7] = 0;
  wc.s[8] = pred_w1;  wc.d[8] = wb_pred1;  wc.n[8] = 512L * 672;   wc.permK[8] = 0;
  wc.ba[0] = bif_b_ih; wc.bb[0] = bif_b_hh; wc.bd[0] = bias_bif;
  wc.ba[1] = bib_b_ih; wc.bb[1] = bib_b_hh; wc.bd[1] = bias_bib;
  wc.ba[2] = enc_b_ih; wc.bb[2] = enc_b_hh; wc.bd[2] = bias_enc;
  wc.ba[3] = dec_b_ih; wc.bb[3] = dec_b_hh; wc.bd[3] = bias_dec;
  wc.cnt = cnt;
  initw_k<<<1024, 256, 0, stream>>>(wc);

  embed_k<<<2048, 256, 0, stream>>>(enc_q, enc_a, enc_pos, enc_fmt,
                                    dec_q, dec_a, dec_pos, dec_fmt, enc_last,
                                    t_emb, a_emb, pos_emb, fmt_emb, enc_x, dec_x);

  // ---- phase 1: bif (fwd) + bib (bwd) persistent chunks -> bi ----
  for (int k = 0; k < NCH; k++) {
    const int t0f = k * CH;
    const int t0b = 256 - (k + 1) * CH;
    XGJob2 j{enc_x + (long)t0f * 256 * 288, enc_x + (long)t0b * 256 * 288,
             wb_bif_ih, wb_bib_ih, bias_bif, bias_bib, X1, X2};
    gemm_xg2_k<<<dim3(16, CH * 2, 2), 256, 0, stream>>>(j);
    SeqP sp{X1, X2, wb_bif_hh, wb_bib_hh, c_bif, c_bib,
            bi, nullptr, nullptr, cnt, k, CH};
    lstm_seq_k<0><<<dim3(256), dim3(512), 0, stream>>>(sp);
  }

  // ---- phase 2: enc LSTM at CHe (xg spans X1|X2), final state only ----
  for (int k = 0; k < NCH2; k++) {
    gemm_tile_k<0, 32><<<dim3(16, CHe * 2), 256, 0, stream>>>(
        bi + (long)k * CHe * SLOT_BI, 1024, bi, 1024, 1024,
        wb_enc_ih, 1024, bias_enc, X1, 2048);
    SeqP sp{X1, nullptr, wb_enc_hh, nullptr, c_enc, nullptr,
            nullptr, h_enc0, h_enc1, cnt + 32L * 32, k, CHe};
    lstm_seq_k<1><<<dim3(128), dim3(512), 0, stream>>>(sp);
  }
  // final h in h_enc0 (t=255 odd -> ho = h0), final c in c_enc

  // ---- phase 3: dec LSTM at CHe -> decout (full buffer in dead bi) ----
  for (int k = 0; k < NCH2; k++) {
    gemm_tile_k<0, 9><<<dim3(16, CHe * 2), 256, 0, stream>>>(
        dec_x + (long)k * CHe * 256 * 288, 288, dec_x, 288, 288,
        wb_dec_ih, 288, bias_dec, X1, 2048);
    SeqP sp{X1, nullptr, wb_dec_hh, nullptr, c_enc, nullptr,
            decout, h_enc0, nullptr, cnt + 48L * 32, k, CHe};
    lstm_seq_k<2><<<dim3(128), dim3(512), 0, stream>>>(sp);
  }

  // ---- head once over full T: hidden = tanh([dec_x[:,:160]|decout]@w1^T+b1) ----
  gemm_tile_k<1, 21><<<dim3(4, 512), 256, 0, stream>>>(
      dec_x, 288, decout, 512, 160, wb_pred1, 672, pred_b1, hidden, 512);
  pred_out_k<<<2048, 256, 0, stream>>>(hidden, pred_w2, pred_b2, (float*)d_out);
}

// Round 18
// 5812.970 us; speedup vs baseline: 1.0615x; 1.0615x over previous
//
#include <hip/hip_runtime.h>

// ---------------------------------------------------------------------------
// SDKT model: embeddings -> biLSTM encoder -> enc LSTM -> dec LSTM -> MLP head
// B=256, T=256, H=512, G=2048, enc/dec input = 288, enc2 input = 1024.
// == r14/r16 configuration (measured best: 5.822 ms, reproduced) ==
// GEMMs: m97-style 128x128 tile, BK=32, global_load_lds(16B), 2-barrier loop,
// LDS XOR-swizzle (pre-swizzled global source + swizzled fragment read;
// 8-way->2-way bank conflict) and PRE-PERMUTED W_ih rows/biases at init so
// xg gate-interleaving is a LINEAR cached write (r17 proved write-through
// epilogues regress; r15 proved fat persistent-panel blocks regress).
// xg layout [row][h][g]: LSTM reads one u64 per (row,hcol).
// Recurrences: persistent chunk kernels (w_hh in VGPRs, agent-atomic h
// exchange, 8-block group barrier, c in regs per chunk). Phases 2/3 at
// CHe=2*CH over the contiguous X1|X2 span. Activations TIME-MAJOR [T][B][*].
// ---------------------------------------------------------------------------

using u16 = unsigned short;
using u32 = unsigned int;
using u64 = unsigned long long;
typedef float f32x4 __attribute__((ext_vector_type(4)));
typedef __bf16 bf16x8 __attribute__((ext_vector_type(8)));

__device__ __forceinline__ u16 f2bf(float f) {
  u32 u = __float_as_uint(f);
  u = (u + 0x7FFFu + ((u >> 16) & 1u)) >> 16;  // RNE
  return (u16)u;
}
__device__ __forceinline__ float bf2f(u16 h) { return __uint_as_float(((u32)h) << 16); }
__device__ __forceinline__ float sigm(float x) { return 1.f / (1.f + __expf(-x)); }
__device__ __forceinline__ float tnh(float x) {
  float a = fabsf(x), e = __expf(-2.f * a);
  float t = (1.f - e) / (1.f + e);
  return x < 0.f ? -t : t;
}
__device__ __forceinline__ u64 ldA_u64(const u16* p) {
  return __hip_atomic_load((const u64*)p, __ATOMIC_RELAXED, __HIP_MEMORY_SCOPE_AGENT);
}
__device__ __forceinline__ void stA_u16(u16* p, u16 v) {
  __hip_atomic_store(p, v, __ATOMIC_RELAXED, __HIP_MEMORY_SCOPE_AGENT);
}
__device__ __forceinline__ void gload_lds16(const u16* g, u16* l) {
  __builtin_amdgcn_global_load_lds(
      (const __attribute__((address_space(1))) unsigned int*)g,
      (__attribute__((address_space(3))) unsigned int*)l, 16, 0, 0);
}

static const long SLOT_BI = 256L * 1024;
static const long SLOT_DO = 256L * 512;
static const long SLOT_XG = 256L * 2048;

// ---------------------------------------------------------------------------
// GEMM body: C = act(A@W^T + bias). Tile 128x128, BK=32, global_load_lds
// staging, 2 barriers/K-step. LDS tiles XOR-SWIZZLED: within each 128B
// row-pair (8 slots of 16B), logical slot s=((row&1)<<2)|q lives at
// s' = s ^ ((row>>1)&7). Staging pre-swizzles the GLOBAL source per lane
// (LDS dest stays linear); fragment reads apply the same XOR.
// ---------------------------------------------------------------------------
template <int ACT, int KSTEPS>
__device__ __forceinline__ void gemm_body(
    const u16* __restrict__ A1, long lda1, const u16* __restrict__ A2, long lda2, int ksplit,
    const u16* __restrict__ W, long ldw, const float* __restrict__ bias,
    u16* __restrict__ C, long ldc, int bx, int by, u16* sA, u16* sB) {
  const int tid = threadIdx.x;
  const int w = tid >> 6, lane = tid & 63;
  const int lr = lane & 15, lg = lane >> 4;
  const long mbase = (long)by * 128;
  const long nbase = (long)bx * 128;
  const int wm = (w >> 1) * 64, wn = (w & 1) * 64;
  // staging decomposition: lane -> linear LDS slot; inverse-swizzle source
  const int s_r = lane >> 2, s_q = lane & 3;
  const int u_ = s_r >> 1;                 // 128B pair index within chunk
  const int sp = ((s_r & 1) << 2) | s_q;   // physical slot within 128B
  const int s_log = sp ^ u_;               // logical slot (involution)
  const int q_log = s_log & 3;             // k-chunk (16B) within row
  const int ric = u_ * 2 + (s_log >> 2);   // logical row within 16-row chunk
  f32x4 acc[4][4] = {};
#pragma unroll 1
  for (int ks = 0; ks < KSTEPS; ks++) {
    const int kk = ks * 32;
    const u16* Asrc;
    long alda;
    int kofs;
    if (kk < ksplit) { Asrc = A1; alda = lda1; kofs = kk; }
    else             { Asrc = A2; alda = lda2; kofs = kk - ksplit; }
#pragma unroll
    for (int j = 0; j < 2; j++) {
      const int c = w * 2 + j;
      const long row = c * 16 + ric;
      gload_lds16(Asrc + (mbase + row) * alda + kofs + q_log * 8, sA + c * 512);
      gload_lds16(W + (nbase + row) * ldw + kk + q_log * 8, sB + c * 512);
    }
    __syncthreads();
    bf16x8 a[4], b[4];
#pragma unroll
    for (int f = 0; f < 4; f++) {
      const int ra = wm + f * 16 + lr;
      const int rb = wn + f * 16 + lr;
      const int oa = (ra >> 1) * 64 + (((((ra & 1) << 2) | lg) ^ ((ra >> 1) & 7)) << 3);
      const int ob = (rb >> 1) * 64 + (((((rb & 1) << 2) | lg) ^ ((rb >> 1) & 7)) << 3);
      a[f] = *reinterpret_cast<const bf16x8*>(sA + oa);
      b[f] = *reinterpret_cast<const bf16x8*>(sB + ob);
    }
#pragma unroll
    for (int fm = 0; fm < 4; fm++)
#pragma unroll
      for (int fn = 0; fn < 4; fn++)
        acc[fm][fn] = __builtin_amdgcn_mfma_f32_16x16x32_bf16(a[fm], b[fn], acc[fm][fn], 0, 0, 0);
    __syncthreads();
  }
#pragma unroll
  for (int fm = 0; fm < 4; fm++)
#pragma unroll
    for (int fn = 0; fn < 4; fn++)
#pragma unroll
      for (int r = 0; r < 4; r++) {
        const long row = mbase + wm + fm * 16 + lg * 4 + r;  // C/D: row=(lane>>4)*4+reg
        const long col = nbase + wn + fn * 16 + lr;          //      col=lane&15
        float v = acc[fm][fn][r] + bias[col];
        if (ACT == 1) v = tnh(v);
        C[row * ldc + col] = f2bf(v);                        // linear (W pre-permuted)
      }
}

template <int ACT, int KSTEPS>
__global__ __launch_bounds__(256) void gemm_tile_k(
    const u16* __restrict__ A1, long lda1, const u16* __restrict__ A2, long lda2, int ksplit,
    const u16* __restrict__ W, long ldw, const float* __restrict__ bias,
    u16* __restrict__ C, long ldc) {
  __shared__ u16 sA[4096];
  __shared__ u16 sB[4096];
  gemm_body<ACT, KSTEPS>(A1, lda1, A2, lda2, ksplit, W, ldw, bias, C, ldc,
                         blockIdx.x, blockIdx.y, sA, sB);
}

// two K=288 xg jobs in one dispatch (z picks bif / bib)
struct XGJob2 {
  const u16 *Aa, *Ab, *Wa, *Wb;
  const float *ba, *bb;
  u16 *Xa, *Xb;
};
__global__ __launch_bounds__(256) void gemm_xg2_k(XGJob2 j) {
  __shared__ u16 sA[4096];
  __shared__ u16 sB[4096];
  if (blockIdx.z == 0)
    gemm_body<0, 9>(j.Aa, 288, nullptr, 0, 1 << 30, j.Wa, 288, j.ba, j.Xa, 2048,
                    blockIdx.x, blockIdx.y, sA, sB);
  else
    gemm_body<0, 9>(j.Ab, 288, nullptr, 0, 1 << 30, j.Wb, 288, j.bb, j.Xb, 2048,
                    blockIdx.x, blockIdx.y, sA, sB);
}

// ---------------------------------------------------------------------------
// Persistent chunk LSTM (r12-proven, generic in CH/k). MODE 0: biLSTM
// (2 dirs, history=bi, stride 1024). MODE 1: enc (ping-pong h0/h1).
// MODE 2: dec (FULL decout buffer, init h0, c continues).
// ---------------------------------------------------------------------------
struct SeqP {
  const u16 *xgA, *xgB;
  const u16 *whA, *whB;
  float *cA, *cB;
  u16 *histA;
  u16 *h0, *h1;
  u32 *cnt;
  int k, CH;
};

template <int MODE>
__global__ __launch_bounds__(512, 2) void lstm_seq_k(SeqP p) {
  const int tid = threadIdx.x;
  const int w = tid >> 6, lane = tid & 63, lr = lane & 15, lg = lane >> 4;
  const int hct = w & 3, kh = w >> 2;
  int dir, rt, kb;
  if (MODE == 0) { dir = blockIdx.x >> 7; rt = (blockIdx.x >> 3) & 15; kb = blockIdx.x & 7; }
  else           { dir = 0;               rt = blockIdx.x >> 3;        kb = blockIdx.x & 7; }
  const u16* xg = (MODE == 0 && dir) ? p.xgB : p.xgA;
  const u16* wh = (MODE == 0 && dir) ? p.whB : p.whA;
  float* cbuf   = (MODE == 0 && dir) ? p.cB  : p.cA;
  const int rbase = rt * 16;
  const int hc0 = kb * 64 + hct * 16;
  const int kofs = kh * 256;
  u32* cnt = p.cnt + (long)((MODE == 0) ? (dir * 16 + rt) : rt) * 32;

  bf16x8 W[4][8];
#pragma unroll
  for (int g = 0; g < 4; g++)
#pragma unroll
    for (int ki = 0; ki < 8; ki++)
      W[g][ki] = *reinterpret_cast<const bf16x8*>(
          wh + (long)(g * 512 + hc0 + lr) * 512 + kofs + ki * 32 + lg * 8);

  const bool zero_init = (MODE <= 1) && (p.k == 0);
  float creg[4];
#pragma unroll
  for (int r = 0; r < 4; r++) {
    creg[r] = 0.f;
    if (kh == 0 && !zero_init)
      creg[r] = cbuf[(long)(rbase + lg * 4 + r) * 512 + hc0 + lr];
  }

  // [hct][g][lane]: lane stride 16B -> conflict-free
  __shared__ f32x4 lacc[4][4][64];  // 16 KB

  for (int ts = 0; ts < p.CH; ts++) {
    const int S = p.k * p.CH + ts;
    const u16* hp;
    u16* ho;
    long hstride;
    int slot;
    bool first;
    if (MODE == 0) {
      const int t = dir == 0 ? S : 255 - S;
      slot = dir == 0 ? ts : p.CH - 1 - ts;
      hstride = 1024;
      const int tp = dir == 0 ? t - 1 : t + 1;
      hp = p.histA + (long)tp * SLOT_BI + dir * 512;
      ho = p.histA + (long)t * SLOT_BI + dir * 512;
      first = (S == 0);
    } else if (MODE == 1) {
      slot = ts; hstride = 512;
      hp = (S & 1) ? p.h1 : p.h0;
      ho = (S & 1) ? p.h0 : p.h1;
      first = (S == 0);
    } else {
      slot = ts; hstride = 512;
      hp = (S == 0) ? p.h0 : p.histA + (long)(S - 1) * SLOT_DO;
      ho = p.histA + (long)S * SLOT_DO;
      first = false;
    }

    // hoisted xg loads: gate-interleaved -> one u64 per r
    u64 xq[4];
    if (kh == 0) {
      const long xb2 = (long)slot * SLOT_XG;
      const int colh = hc0 + lr;
#pragma unroll
      for (int r = 0; r < 4; r++)
        xq[r] = *reinterpret_cast<const u64*>(
            xg + xb2 + (long)(rbase + lg * 4 + r) * 2048 + colh * 4);
    }

    f32x4 acc[4] = {};
    if (!first) {
      union AU { u64 q[2]; bf16x8 v; } au[8];
      const u16* abase = hp + (long)(rbase + lr) * hstride + kofs;
#pragma unroll
      for (int ki = 0; ki < 8; ki++) {
        au[ki].q[0] = ldA_u64(abase + ki * 32 + lg * 8);
        au[ki].q[1] = ldA_u64(abase + ki * 32 + lg * 8 + 4);
      }
#pragma unroll
      for (int ki = 0; ki < 8; ki++) {
#pragma unroll
        for (int g = 0; g < 4; g++)
          acc[g] = __builtin_amdgcn_mfma_f32_16x16x32_bf16(au[ki].v, W[g][ki], acc[g], 0, 0, 0);
      }
    }
    if (kh == 1) {
#pragma unroll
      for (int g = 0; g < 4; g++) lacc[hct][g][lane] = acc[g];
    }
    __syncthreads();
    if (kh == 0) {
#pragma unroll
      for (int g = 0; g < 4; g++) acc[g] += lacc[hct][g][lane];
#pragma unroll
      for (int r = 0; r < 4; r++) {
        const long row = rbase + lg * 4 + r;
        const int colh = hc0 + lr;
        float gi = acc[0][r] + bf2f((u16)(xq[r]));
        float gf = acc[1][r] + bf2f((u16)(xq[r] >> 16));
        float gg = acc[2][r] + bf2f((u16)(xq[r] >> 32));
        float go = acc[3][r] + bf2f((u16)(xq[r] >> 48));
        float cn = sigm(gf) * creg[r] + sigm(gi) * tnh(gg);
        creg[r] = cn;
        stA_u16(&ho[row * hstride + colh], f2bf(sigm(go) * tnh(cn)));
      }
    }
    __syncthreads();  // vmcnt(0) drained: h stores at coherence point
    if (tid == 0) {
      __hip_atomic_fetch_add(cnt, 1u, __ATOMIC_RELAXED, __HIP_MEMORY_SCOPE_AGENT);
      if (ts != p.CH - 1) {
        const u32 tgt = 8u * (u32)(S + 1);
        while (__hip_atomic_load(cnt, __ATOMIC_RELAXED, __HIP_MEMORY_SCOPE_AGENT) < tgt)
          __builtin_amdgcn_s_sleep(1);
      }
    }
    __syncthreads();
  }
  if (kh == 0) {
#pragma unroll
    for (int r = 0; r < 4; r++)
      cbuf[(long)(rbase + lg * 4 + r) * 512 + hc0 + lr] = creg[r];
  }
}

// ---------------------------------------------------------------------------
// Init: weight converts (w_ih ROWS PERMUTED to gate-interleave: row' =
// (row&511)*4 + row>>9), bias folds (permuted), counter zero — ONE dispatch.
// ---------------------------------------------------------------------------
struct WcvP {
  const float* s[9]; u16* d[9]; long n[9]; int permK[9];
  const float *ba[4], *bb[4]; float* bd[4];
  u32* cnt;
};
__global__ __launch_bounds__(256) void initw_k(WcvP w) {
  const long g0 = (long)blockIdx.x * 256 + threadIdx.x;
  const long gs = (long)gridDim.x * 256;
  for (int seg = 0; seg < 9; seg++) {
    const int K = w.permK[seg];
    if (K) {
      for (long i = g0; i < w.n[seg]; i += gs) {
        const long row = i / K, kk = i - row * K;
        const long pr = ((row & 511) << 2) | (row >> 9);
        w.d[seg][pr * K + kk] = f2bf(w.s[seg][i]);
      }
    } else {
      for (long i = g0; i < w.n[seg]; i += gs) w.d[seg][i] = f2bf(w.s[seg][i]);
    }
  }
  for (int seg = 0; seg < 4; seg++)
    for (long i = g0; i < 2048; i += gs) {
      const long pi = ((i & 511) << 2) | (i >> 9);
      w.bd[seg][pi] = w.ba[seg][i] + w.bb[seg][i];
    }
  for (long i = g0; i < 64 * 32; i += gs) w.cnt[i] = 0;
}

// ---------------------------------------------------------------------------
// Both embedding gathers in ONE kernel -> bf16, TIME-MAJOR (row = t*256+b).
// ---------------------------------------------------------------------------
__global__ __launch_bounds__(256) void embed_k(
    const int* __restrict__ eq, const int* __restrict__ ea, const int* __restrict__ epos,
    const int* __restrict__ efmt, const int* __restrict__ dq, const int* __restrict__ da,
    const int* __restrict__ dpos, const int* __restrict__ dfmt, const int* __restrict__ last_a,
    const float* __restrict__ tw, const float* __restrict__ aw,
    const float* __restrict__ pw, const float* __restrict__ fw,
    u16* __restrict__ eout, u16* __restrict__ dout) {
  for (long row = blockIdx.x; row < 65536; row += gridDim.x) {
    const int t = (int)(row >> 8), b = (int)(row & 255);
    const long src = (long)b * 256 + t;  // inputs are [B][T]
    {
      const int iq = eq[src], ia = ea[src], ip = epos[src], ifm = efmt[src];
      for (int col = threadIdx.x; col < 288; col += 256) {
        float v;
        if (col < 128)      v = tw[(long)iq * 128 + col];
        else if (col < 256) v = aw[(long)ia * 128 + (col - 128)];
        else if (col < 272) v = pw[(long)ip * 16 + (col - 256)];
        else                v = fw[(long)ifm * 16 + (col - 272)];
        eout[row * 288 + col] = f2bf(v);
      }
    }
    {
      const int iq = dq[src], ip = dpos[src], ifm = dfmt[src];
      const int pa = (t == 0) ? last_a[b] : da[src - 1];  // teacher forcing shift
      for (int col = threadIdx.x; col < 288; col += 256) {
        float v;
        if (col < 128)      v = tw[(long)iq * 128 + col];
        else if (col < 144) v = pw[(long)ip * 16 + (col - 128)];
        else if (col < 160) v = fw[(long)ifm * 16 + (col - 144)];
        else                v = aw[(long)pa * 128 + (col - 160)];
        dout[row * 288 + col] = f2bf(v);
      }
    }
  }
}

// out[b*256+t] = sigmoid(hidden[t*256+b] . w2 + b2); grid-stride, 1 wave/row.
__global__ __launch_bounds__(256) void pred_out_k(
    const u16* __restrict__ hidden, const float* __restrict__ w2,
    const float* __restrict__ b2, float* __restrict__ out) {
  const int lane = threadIdx.x & 63;
  const float* wp = w2 + lane * 8;
  float wv[8];
#pragma unroll
  for (int j = 0; j < 8; j++) wv[j] = wp[j];
  const float bv = b2[0];
  for (long r = (long)blockIdx.x * 4 + (threadIdx.x >> 6); r < 65536; r += 8192) {
    const u16* hp = hidden + r * 512 + lane * 8;
    float s = 0.f;
#pragma unroll
    for (int j = 0; j < 8; j++) s += bf2f(hp[j]) * wv[j];
    for (int off = 32; off > 0; off >>= 1) s += __shfl_down(s, off);
    if (lane == 0) out[(r & 255) * 256 + (r >> 8)] = sigm(s + bv);
  }
}

// ---------------------------------------------------------------------------
extern "C" void kernel_launch(void* const* d_in, const int* in_sizes, int n_in,
                              void* d_out, int out_size, void* d_ws, size_t ws_size,
                              hipStream_t stream) {
  const int* enc_q     = (const int*)d_in[0];
  const int* enc_a     = (const int*)d_in[1];
  const int* enc_pos   = (const int*)d_in[2];
  const int* enc_fmt   = (const int*)d_in[3];
  const int* dec_q     = (const int*)d_in[4];
  const int* dec_a     = (const int*)d_in[5];
  const int* dec_pos   = (const int*)d_in[6];
  const int* dec_fmt   = (const int*)d_in[7];
  const int* enc_last  = (const int*)d_in[8];
  const float* t_emb   = (const float*)d_in[9];
  const float* a_emb   = (const float*)d_in[10];
  const float* pos_emb = (const float*)d_in[11];
  const float* fmt_emb = (const float*)d_in[12];
  const float* bif_w_ih = (const float*)d_in[13];
  const float* bif_w_hh = (const float*)d_in[14];
  const float* bif_b_ih = (const float*)d_in[15];
  const float* bif_b_hh = (const float*)d_in[16];
  const float* bib_w_ih = (const float*)d_in[17];
  const float* bib_w_hh = (const float*)d_in[18];
  const float* bib_b_ih = (const float*)d_in[19];
  const float* bib_b_hh = (const float*)d_in[20];
  const float* enc_w_ih = (const float*)d_in[21];
  const float* enc_w_hh = (const float*)d_in[22];
  const float* enc_b_ih = (const float*)d_in[23];
  const float* enc_b_hh = (const float*)d_in[24];
  const float* dec_w_ih = (const float*)d_in[25];
  const float* dec_w_hh = (const float*)d_in[26];
  const float* dec_b_ih = (const float*)d_in[27];
  const float* dec_b_hh = (const float*)d_in[28];
  const float* pred_w1 = (const float*)d_in[29];
  const float* pred_b1 = (const float*)d_in[30];
  const float* pred_w2 = (const float*)d_in[31];
  const float* pred_b2 = (const float*)d_in[32];
  (void)in_sizes; (void)n_in; (void)out_size;

  char* base = (char*)d_ws;
  size_t off = 0;
  auto alloc = [&](size_t bytes) -> char* {
    char* p = base + off;
    off = (off + bytes + 255) & ~(size_t)255;
    return p;
  };

  // --- fixed region ---
  u16* wb_bif_ih = (u16*)alloc(2048L * 288 * 2);
  u16* wb_bib_ih = (u16*)alloc(2048L * 288 * 2);
  u16* wb_enc_ih = (u16*)alloc(2048L * 1024 * 2);
  u16* wb_dec_ih = (u16*)alloc(2048L * 288 * 2);
  u16* wb_bif_hh = (u16*)alloc(2048L * 512 * 2);
  u16* wb_bib_hh = (u16*)alloc(2048L * 512 * 2);
  u16* wb_enc_hh = (u16*)alloc(2048L * 512 * 2);
  u16* wb_dec_hh = (u16*)alloc(2048L * 512 * 2);
  u16* wb_pred1  = (u16*)alloc(512L * 672 * 2);
  float* bias_bif = (float*)alloc(2048 * 4);
  float* bias_bib = (float*)alloc(2048 * 4);
  float* bias_enc = (float*)alloc(2048 * 4);
  float* bias_dec = (float*)alloc(2048 * 4);
  float* c_bif = (float*)alloc(256L * 512 * 4);
  float* c_bib = (float*)alloc(256L * 512 * 4);
  float* c_enc = (float*)alloc(256L * 512 * 4);
  u16* h_enc0 = (u16*)alloc(256L * 512 * 2);
  u16* h_enc1 = (u16*)alloc(256L * 512 * 2);
  u32* cnt = (u32*)alloc(64L * 32 * 4);

  // --- big activations (time-major) ---
  u16* bi    = (u16*)alloc(65536L * 1024 * 2);  // phase1/2; decout+hidden alias
  u16* dec_x = (u16*)alloc(65536L * 288 * 2);
  u16* enc_x = (u16*)alloc(65536L * 288 * 2);

  int CH = 128;
  while (CH > 8 && off + 2ull * CH * 256 * 2048 * 2 > ws_size) CH >>= 1;
  u16* X1 = (u16*)alloc((size_t)CH * 256 * 2048 * 2);
  u16* X2 = (u16*)alloc((size_t)CH * 256 * 2048 * 2);  // contiguous after X1
  u16* decout = bi;                 // [65536][512], bi dead after phase 2
  u16* hidden = bi + 65536L * 512;  // [65536][512]
  const int NCH = 256 / CH;
  const int CHe = (CH * 2 <= 256) ? CH * 2 : 256;  // phases 2/3 use X1|X2 span
  const int NCH2 = 256 / CHe;

  WcvP wc;
  wc.s[0] = bif_w_ih; wc.d[0] = wb_bif_ih; wc.n[0] = 2048L * 288;  wc.permK[0] = 288;
  wc.s[1] = bib_w_ih; wc.d[1] = wb_bib_ih; wc.n[1] = 2048L * 288;  wc.permK[1] = 288;
  wc.s[2] = enc_w_ih; wc.d[2] = wb_enc_ih; wc.n[2] = 2048L * 1024; wc.permK[2] = 1024;
  wc.s[3] = dec_w_ih; wc.d[3] = wb_dec_ih; wc.n[3] = 2048L * 288;  wc.permK[3] = 288;
  wc.s[4] = bif_w_hh; wc.d[4] = wb_bif_hh; wc.n[4] = 2048L * 512;  wc.permK[4] = 0;
  wc.s[5] = bib_w_hh; wc.d[5] = wb_bib_hh; wc.n[5] = 2048L * 512;  wc.permK[5] = 0;
  wc.s[6] = enc_w_hh; wc.d[6] = wb_enc_hh; wc.n[6] = 2048L * 512;  wc.permK[6] = 0;
  wc.s[7] = dec_w_hh; wc.d[7] = wb_dec_hh; wc.n[7] = 2048L * 512;  wc.permK[7] = 0;
  wc.s[8] = pred_w1;  wc.d[8] = wb_pred1;  wc.n[8] = 512L * 672;   wc.permK[8] = 0;
  wc.ba[0] = bif_b_ih; wc.bb[0] = bif_b_hh; wc.bd[0] = bias_bif;
  wc.ba[1] = bib_b_ih; wc.bb[1] = bib_b_hh; wc.bd[1] = bias_bib;
  wc.ba[2] = enc_b_ih; wc.bb[2] = enc_b_hh; wc.bd[2] = bias_enc;
  wc.ba[3] = dec_b_ih; wc.bb[3] = dec_b_hh; wc.bd[3] = bias_dec;
  wc.cnt = cnt;
  initw_k<<<1024, 256, 0, stream>>>(wc);

  embed_k<<<2048, 256, 0, stream>>>(enc_q, enc_a, enc_pos, enc_fmt,
                                    dec_q, dec_a, dec_pos, dec_fmt, enc_last,
                                    t_emb, a_emb, pos_emb, fmt_emb, enc_x, dec_x);

  // ---- phase 1: bif (fwd) + bib (bwd) persistent chunks -> bi ----
  for (int k = 0; k < NCH; k++) {
    const int t0f = k * CH;
    const int t0b = 256 - (k + 1) * CH;
    XGJob2 j{enc_x + (long)t0f * 256 * 288, enc_x + (long)t0b * 256 * 288,
             wb_bif_ih, wb_bib_ih, bias_bif, bias_bib, X1, X2};
    gemm_xg2_k<<<dim3(16, CH * 2, 2), 256, 0, stream>>>(j);
    SeqP sp{X1, X2, wb_bif_hh, wb_bib_hh, c_bif, c_bib,
            bi, nullptr, nullptr, cnt, k, CH};
    lstm_seq_k<0><<<dim3(256), dim3(512), 0, stream>>>(sp);
  }

  // ---- phase 2: enc LSTM at CHe (xg spans X1|X2), final state only ----
  for (int k = 0; k < NCH2; k++) {
    gemm_tile_k<0, 32><<<dim3(16, CHe * 2), 256, 0, stream>>>(
        bi + (long)k * CHe * SLOT_BI, 1024, bi, 1024, 1024,
        wb_enc_ih, 1024, bias_enc, X1, 2048);
    SeqP sp{X1, nullptr, wb_enc_hh, nullptr, c_enc, nullptr,
            nullptr, h_enc0, h_enc1, cnt + 32L * 32, k, CHe};
    lstm_seq_k<1><<<dim3(128), dim3(512), 0, stream>>>(sp);
  }
  // final h in h_enc0 (t=255 odd -> ho = h0), final c in c_enc

  // ---- phase 3: dec LSTM at CHe -> decout (full buffer in dead bi) ----
  for (int k = 0; k < NCH2; k++) {
    gemm_tile_k<0, 9><<<dim3(16, CHe * 2), 256, 0, stream>>>(
        dec_x + (long)k * CHe * 256 * 288, 288, dec_x, 288, 288,
        wb_dec_ih, 288, bias_dec, X1, 2048);
    SeqP sp{X1, nullptr, wb_dec_hh, nullptr, c_enc, nullptr,
            decout, h_enc0, nullptr, cnt + 48L * 32, k, CHe};
    lstm_seq_k<2><<<dim3(128), dim3(512), 0, stream>>>(sp);
  }

  // ---- head once over full T: hidden = tanh([dec_x[:,:160]|decout]@w1^T+b1) ----
  gemm_tile_k<1, 21><<<dim3(4, 512), 256, 0, stream>>>(
      dec_x, 288, decout, 512, 160, wb_pred1, 672, pred_b1, hidden, 512);
  pred_out_k<<<2048, 256, 0, stream>>>(hidden, pred_w2, pred_b2, (float*)d_out);
}